// Round 1
// baseline (344.966 us; speedup 1.0000x reference)
//
#include <hip/hip_runtime.h>
#include <stdint.h>

// Problem constants
#define BB 2
#define SS 2048
#define DD 1024
#define HH 16
#define DHH 64
#define NEGV -1.0e9f

typedef __bf16 bf16_t;
typedef bf16_t bf16x8 __attribute__((ext_vector_type(8)));
typedef float f32x4 __attribute__((ext_vector_type(4)));

union FragU { uint4 u; bf16x8 b; };

__device__ __forceinline__ unsigned short f2bf(float f) {
  union { float f; unsigned int u; } x; x.f = f;
  unsigned int u = x.u;
  return (unsigned short)((u + 0x7FFFu + ((u >> 16) & 1u)) >> 16);  // RNE
}

__device__ __forceinline__ uint2 pack4(float4 v) {
  uint2 r;
  r.x = (unsigned)f2bf(v.x) | ((unsigned)f2bf(v.y) << 16);
  r.y = (unsigned)f2bf(v.z) | ((unsigned)f2bf(v.w) << 16);
  return r;
}

__device__ __forceinline__ bf16x8 ldsFrag(const unsigned short* s, int idx) {
  FragU f;
  f.u = *reinterpret_cast<const uint4*>(s + idx);
  return f.b;
}

#define MFMA16(a, b, c) __builtin_amdgcn_mfma_f32_16x16x32_bf16((a), (b), (c), 0, 0, 0)

// C = A(fp32, MxK) * W(fp32, NxK)^T, output bf16 scattered.
// layout 0: Out[b][h][s][dh]  (Q, K)
// layout 1: Out[b][h][dh][s]  (V transposed for PV B^T form)
__global__ __launch_bounds__(256) void proj_kernel(
    const float* __restrict__ A, const float* __restrict__ W,
    unsigned short* __restrict__ Out, int layout) {
  __shared__ unsigned short sA[64 * 72];
  __shared__ unsigned short sW[64 * 72];
  const int t = threadIdx.x;
  const int lane = t & 63, wave = t >> 6;
  const int quad = lane >> 4, l15 = lane & 15;
  const int wr = wave >> 1, wc = wave & 1;
  const int mBase = blockIdx.x * 64, nBase = blockIdx.y * 64;
  const int row = t >> 2, cg = t & 3;

  f32x4 acc[2][2] = {};

  for (int k0 = 0; k0 < DD; k0 += 64) {
    // Stage A tile (64x64 fp32 -> bf16 LDS) : 16 floats per thread
    {
      const float* src = A + (size_t)(mBase + row) * DD + k0 + cg * 16;
      uint2 p0 = pack4(*reinterpret_cast<const float4*>(src + 0));
      uint2 p1 = pack4(*reinterpret_cast<const float4*>(src + 4));
      uint2 p2 = pack4(*reinterpret_cast<const float4*>(src + 8));
      uint2 p3 = pack4(*reinterpret_cast<const float4*>(src + 12));
      uint4 w0; w0.x = p0.x; w0.y = p0.y; w0.z = p1.x; w0.w = p1.y;
      uint4 w1; w1.x = p2.x; w1.y = p2.y; w1.z = p3.x; w1.w = p3.y;
      *reinterpret_cast<uint4*>(&sA[row * 72 + cg * 16]) = w0;
      *reinterpret_cast<uint4*>(&sA[row * 72 + cg * 16 + 8]) = w1;

      const float* srcW = W + (size_t)(nBase + row) * DD + k0 + cg * 16;
      uint2 q0 = pack4(*reinterpret_cast<const float4*>(srcW + 0));
      uint2 q1 = pack4(*reinterpret_cast<const float4*>(srcW + 4));
      uint2 q2 = pack4(*reinterpret_cast<const float4*>(srcW + 8));
      uint2 q3 = pack4(*reinterpret_cast<const float4*>(srcW + 12));
      uint4 u0; u0.x = q0.x; u0.y = q0.y; u0.z = q1.x; u0.w = q1.y;
      uint4 u1; u1.x = q2.x; u1.y = q2.y; u1.z = q3.x; u1.w = q3.y;
      *reinterpret_cast<uint4*>(&sW[row * 72 + cg * 16]) = u0;
      *reinterpret_cast<uint4*>(&sW[row * 72 + cg * 16 + 8]) = u1;
    }
    __syncthreads();

    #pragma unroll
    for (int kk = 0; kk < 2; ++kk) {
      bf16x8 a0 = ldsFrag(sA, (wr * 32 + l15) * 72 + kk * 32 + quad * 8);
      bf16x8 a1 = ldsFrag(sA, (wr * 32 + 16 + l15) * 72 + kk * 32 + quad * 8);
      bf16x8 b0 = ldsFrag(sW, (wc * 32 + l15) * 72 + kk * 32 + quad * 8);
      bf16x8 b1 = ldsFrag(sW, (wc * 32 + 16 + l15) * 72 + kk * 32 + quad * 8);
      acc[0][0] = MFMA16(a0, b0, acc[0][0]);
      acc[0][1] = MFMA16(a0, b1, acc[0][1]);
      acc[1][0] = MFMA16(a1, b0, acc[1][0]);
      acc[1][1] = MFMA16(a1, b1, acc[1][1]);
    }
    __syncthreads();
  }

  // Store scattered bf16. C/D layout: row = quad*4 + r, col = l15 per 16x16 tile.
  #pragma unroll
  for (int i = 0; i < 2; ++i) {
    #pragma unroll
    for (int j = 0; j < 2; ++j) {
      #pragma unroll
      for (int r = 0; r < 4; ++r) {
        int m = mBase + wr * 32 + i * 16 + quad * 4 + r;
        int n = nBase + wc * 32 + j * 16 + l15;
        int b = m >> 11, s = m & (SS - 1);
        int h = n >> 6, dh = n & (DHH - 1);
        size_t off;
        if (layout == 0)
          off = ((size_t)(b * HH + h) * SS + s) * DHH + dh;
        else
          off = ((size_t)(b * HH + h) * DHH + dh) * SS + s;
        Out[off] = f2bf(acc[i][j][r]);
      }
    }
  }
}

// Flash attention: one block per (qt, h, b). 4 waves x 16 q-rows each.
__global__ __launch_bounds__(256) void attn_kernel(
    const unsigned short* __restrict__ Qb, const unsigned short* __restrict__ Kb,
    const unsigned short* __restrict__ Vt, const int* __restrict__ mask,
    unsigned short* __restrict__ Ob) {
  __shared__ unsigned short sQ[64 * 72];
  __shared__ unsigned short sK[64 * 72];
  __shared__ unsigned short sV[64 * 72];
  __shared__ unsigned short sP[64 * 72];
  __shared__ float sPad[64];

  const int t = threadIdx.x;
  const int lane = t & 63, wave = t >> 6;
  const int quad = lane >> 4, l15 = lane & 15;
  const int qt = blockIdx.x, h = blockIdx.y, b = blockIdx.z;
  const int qb = qt * 64;
  const size_t headOff = (size_t)(b * HH + h) * SS * DHH;
  const unsigned short* Qh = Qb + headOff;  // [S][64]
  const unsigned short* Kh = Kb + headOff;  // [S][64]
  const unsigned short* Vh = Vt + headOff;  // [64][S]
  const int row = t >> 2, cg = t & 3;

  // Stage Q tile once
  {
    const uint4* src = reinterpret_cast<const uint4*>(Qh + (size_t)(qb + row) * DHH + cg * 16);
    *reinterpret_cast<uint4*>(&sQ[row * 72 + cg * 16]) = src[0];
    *reinterpret_cast<uint4*>(&sQ[row * 72 + cg * 16 + 8]) = src[1];
  }
  __syncthreads();

  bf16x8 aq[2];
  #pragma unroll
  for (int kk = 0; kk < 2; ++kk)
    aq[kk] = ldsFrag(sQ, (wave * 16 + l15) * 72 + kk * 32 + quad * 8);

  float m_r[4], l_r[4];
  f32x4 oacc[4] = {};
  #pragma unroll
  for (int r = 0; r < 4; ++r) { m_r[r] = -1e30f; l_r[r] = 0.0f; }

  for (int kt = 0; kt <= qt; ++kt) {
    // Stage K tile, V^T tile, padding mask
    {
      const uint4* srcK = reinterpret_cast<const uint4*>(Kh + (size_t)(kt * 64 + row) * DHH + cg * 16);
      *reinterpret_cast<uint4*>(&sK[row * 72 + cg * 16]) = srcK[0];
      *reinterpret_cast<uint4*>(&sK[row * 72 + cg * 16 + 8]) = srcK[1];
      const uint4* srcV = reinterpret_cast<const uint4*>(Vh + (size_t)row * SS + kt * 64 + cg * 16);
      *reinterpret_cast<uint4*>(&sV[row * 72 + cg * 16]) = srcV[0];
      *reinterpret_cast<uint4*>(&sV[row * 72 + cg * 16 + 8]) = srcV[1];
      if (t < 64) sPad[t] = (mask[b * SS + kt * 64 + t] == 0) ? NEGV : 0.0f;
    }
    __syncthreads();

    // S = Q K^T for this wave's 16 q-rows x 64 keys
    f32x4 sacc[4] = {};
    #pragma unroll
    for (int kk = 0; kk < 2; ++kk) {
      #pragma unroll
      for (int j = 0; j < 4; ++j) {
        bf16x8 bk = ldsFrag(sK, (j * 16 + l15) * 72 + kk * 32 + quad * 8);
        sacc[j] = MFMA16(aq[kk], bk, sacc[j]);
      }
    }

    const bool diag = (kt == qt);
    float alpha[4];
    #pragma unroll
    for (int r = 0; r < 4; ++r) {
      const int q = qb + wave * 16 + quad * 4 + r;
      float rowmax = -1e30f;
      #pragma unroll
      for (int j = 0; j < 4; ++j) {
        const int k = kt * 64 + j * 16 + l15;
        float sv = sacc[j][r] * 0.125f + sPad[j * 16 + l15];
        if (diag && k > q) sv = NEGV;
        sacc[j][r] = sv;
        rowmax = fmaxf(rowmax, sv);
      }
      // reduce over 16 lanes holding this row's columns
      #pragma unroll
      for (int off = 1; off < 16; off <<= 1)
        rowmax = fmaxf(rowmax, __shfl_xor(rowmax, off));
      const float mnew = fmaxf(m_r[r], rowmax);
      alpha[r] = __expf(m_r[r] - mnew);
      m_r[r] = mnew;
      float rs = 0.0f;
      #pragma unroll
      for (int j = 0; j < 4; ++j) {
        float p = __expf(sacc[j][r] - mnew);
        rs += p;
        sP[(wave * 16 + quad * 4 + r) * 72 + j * 16 + l15] = f2bf(p);
      }
      #pragma unroll
      for (int off = 1; off < 16; off <<= 1)
        rs += __shfl_xor(rs, off);
      l_r[r] = l_r[r] * alpha[r] + rs;
    }

    // Rescale O accumulator
    #pragma unroll
    for (int jn = 0; jn < 4; ++jn) {
      #pragma unroll
      for (int r = 0; r < 4; ++r)
        oacc[jn][r] *= alpha[r];
    }

    // O += P V  (P from per-wave LDS region, V^T gives B^T form)
    #pragma unroll
    for (int kk = 0; kk < 2; ++kk) {
      bf16x8 ap = ldsFrag(sP, (wave * 16 + l15) * 72 + kk * 32 + quad * 8);
      #pragma unroll
      for (int jn = 0; jn < 4; ++jn) {
        bf16x8 bv = ldsFrag(sV, (jn * 16 + l15) * 72 + kk * 32 + quad * 8);
        oacc[jn] = MFMA16(ap, bv, oacc[jn]);
      }
    }
    __syncthreads();
  }

  // Normalize and store O as bf16 [B][S][D] (merged heads)
  #pragma unroll
  for (int r = 0; r < 4; ++r) {
    const float inv = 1.0f / l_r[r];
    const int q = qb + wave * 16 + quad * 4 + r;
    #pragma unroll
    for (int jn = 0; jn < 4; ++jn) {
      const int col = h * DHH + jn * 16 + l15;
      Ob[(size_t)(b * SS + q) * DD + col] = f2bf(oacc[jn][r] * inv);
    }
  }
}

// out = O(bf16, MxK) * Wo(fp32, NxK)^T, fp32 output [M][N]
__global__ __launch_bounds__(256) void outproj_kernel(
    const unsigned short* __restrict__ Ag, const float* __restrict__ W,
    float* __restrict__ Out) {
  __shared__ unsigned short sA[64 * 72];
  __shared__ unsigned short sW[64 * 72];
  const int t = threadIdx.x;
  const int lane = t & 63, wave = t >> 6;
  const int quad = lane >> 4, l15 = lane & 15;
  const int wr = wave >> 1, wc = wave & 1;
  const int mBase = blockIdx.x * 64, nBase = blockIdx.y * 64;
  const int row = t >> 2, cg = t & 3;

  f32x4 acc[2][2] = {};

  for (int k0 = 0; k0 < DD; k0 += 64) {
    {
      const uint4* src = reinterpret_cast<const uint4*>(Ag + (size_t)(mBase + row) * DD + k0 + cg * 16);
      *reinterpret_cast<uint4*>(&sA[row * 72 + cg * 16]) = src[0];
      *reinterpret_cast<uint4*>(&sA[row * 72 + cg * 16 + 8]) = src[1];

      const float* srcW = W + (size_t)(nBase + row) * DD + k0 + cg * 16;
      uint2 q0 = pack4(*reinterpret_cast<const float4*>(srcW + 0));
      uint2 q1 = pack4(*reinterpret_cast<const float4*>(srcW + 4));
      uint2 q2 = pack4(*reinterpret_cast<const float4*>(srcW + 8));
      uint2 q3 = pack4(*reinterpret_cast<const float4*>(srcW + 12));
      uint4 u0; u0.x = q0.x; u0.y = q0.y; u0.z = q1.x; u0.w = q1.y;
      uint4 u1; u1.x = q2.x; u1.y = q2.y; u1.z = q3.x; u1.w = q3.y;
      *reinterpret_cast<uint4*>(&sW[row * 72 + cg * 16]) = u0;
      *reinterpret_cast<uint4*>(&sW[row * 72 + cg * 16 + 8]) = u1;
    }
    __syncthreads();

    #pragma unroll
    for (int kk = 0; kk < 2; ++kk) {
      bf16x8 a0 = ldsFrag(sA, (wr * 32 + l15) * 72 + kk * 32 + quad * 8);
      bf16x8 a1 = ldsFrag(sA, (wr * 32 + 16 + l15) * 72 + kk * 32 + quad * 8);
      bf16x8 b0 = ldsFrag(sW, (wc * 32 + l15) * 72 + kk * 32 + quad * 8);
      bf16x8 b1 = ldsFrag(sW, (wc * 32 + 16 + l15) * 72 + kk * 32 + quad * 8);
      acc[0][0] = MFMA16(a0, b0, acc[0][0]);
      acc[0][1] = MFMA16(a0, b1, acc[0][1]);
      acc[1][0] = MFMA16(a1, b0, acc[1][0]);
      acc[1][1] = MFMA16(a1, b1, acc[1][1]);
    }
    __syncthreads();
  }

  #pragma unroll
  for (int i = 0; i < 2; ++i) {
    #pragma unroll
    for (int j = 0; j < 2; ++j) {
      #pragma unroll
      for (int r = 0; r < 4; ++r) {
        int m = mBase + wr * 32 + i * 16 + quad * 4 + r;
        int n = nBase + wc * 32 + j * 16 + l15;
        Out[(size_t)m * DD + n] = acc[i][j][r];
      }
    }
  }
}

extern "C" void kernel_launch(void* const* d_in, const int* in_sizes, int n_in,
                              void* d_out, int out_size, void* d_ws, size_t ws_size,
                              hipStream_t stream) {
  (void)in_sizes; (void)n_in; (void)out_size; (void)ws_size;
  const float* q  = (const float*)d_in[0];
  const float* k  = (const float*)d_in[1];
  const float* v  = (const float*)d_in[2];
  const int* mask = (const int*)d_in[3];
  const float* Wq = (const float*)d_in[4];
  const float* Wk = (const float*)d_in[5];
  const float* Wv = (const float*)d_in[6];
  const float* Wo = (const float*)d_in[7];
  float* out = (float*)d_out;

  const size_t headElems = (size_t)BB * HH * SS * DHH;  // 4M elements
  unsigned short* Qb = (unsigned short*)d_ws;
  unsigned short* Kb = Qb + headElems;
  unsigned short* Vt = Kb + headElems;
  unsigned short* Ob = Vt + headElems;

  dim3 gProj(BB * SS / 64, DD / 64);  // (64, 16)
  proj_kernel<<<gProj, 256, 0, stream>>>(q, Wq, Qb, 0);
  proj_kernel<<<gProj, 256, 0, stream>>>(k, Wk, Kb, 0);
  proj_kernel<<<gProj, 256, 0, stream>>>(v, Wv, Vt, 1);

  dim3 gAttn(SS / 64, HH, BB);  // (32, 16, 2)
  attn_kernel<<<gAttn, 256, 0, stream>>>(Qb, Kb, Vt, mask, Ob);

  outproj_kernel<<<gProj, 256, 0, stream>>>(Ob, Wo, out);
}

// Round 2
// 298.383 us; speedup vs baseline: 1.1561x; 1.1561x over previous
//
#include <hip/hip_runtime.h>
#include <stdint.h>

// Problem constants
#define BB 2
#define SS 2048
#define DD 1024
#define HH 16
#define DHH 64
#define NEGV -1.0e9f

typedef __bf16 bf16_t;
typedef bf16_t bf16x8 __attribute__((ext_vector_type(8)));
typedef float f32x4 __attribute__((ext_vector_type(4)));

union FragU { uint4 u; bf16x8 b; };

__device__ __forceinline__ unsigned short f2bf(float f) {
  union { float f; unsigned int u; } x; x.f = f;
  unsigned int u = x.u;
  return (unsigned short)((u + 0x7FFFu + ((u >> 16) & 1u)) >> 16);  // RNE
}

__device__ __forceinline__ uint2 pack4(float4 v) {
  uint2 r;
  r.x = (unsigned)f2bf(v.x) | ((unsigned)f2bf(v.y) << 16);
  r.y = (unsigned)f2bf(v.z) | ((unsigned)f2bf(v.w) << 16);
  return r;
}

__device__ __forceinline__ bf16x8 ldsFrag(const unsigned short* s, int idx) {
  FragU f;
  f.u = *reinterpret_cast<const uint4*>(s + idx);
  return f.b;
}

// async global -> LDS, 16 bytes per lane. LDS dest = wave-uniform base + lane*16.
__device__ __forceinline__ void gload_lds16(const unsigned short* g, unsigned short* s) {
  __builtin_amdgcn_global_load_lds(
      (const __attribute__((address_space(1))) unsigned int*)g,
      (__attribute__((address_space(3))) unsigned int*)s, 16, 0, 0);
}

#define MFMA16(a, b, c) __builtin_amdgcn_mfma_f32_16x16x32_bf16((a), (b), (c), 0, 0, 0)

// ---------------- weight fp32 -> bf16 convert (all 4 weights) ----------------
__global__ __launch_bounds__(256) void convert_kernel(
    const float* __restrict__ w0, const float* __restrict__ w1,
    const float* __restrict__ w2, const float* __restrict__ w3,
    unsigned short* __restrict__ out) {
  const int z = blockIdx.y;
  const float* w = (z == 0) ? w0 : (z == 1) ? w1 : (z == 2) ? w2 : w3;
  const size_t base = (size_t)blockIdx.x * 1024 + (size_t)threadIdx.x * 4;
  float4 v = *reinterpret_cast<const float4*>(w + base);
  uint2 p = pack4(v);
  *reinterpret_cast<uint2*>(out + (size_t)z * DD * DD + base) = p;
}

// ---------------- Q/K/V projections, fused into one launch ----------------
// C = A(fp32, MxK) * W(bf16, NxK)^T ; 128x128 tile, BK=64.
// z=0: Q -> [b][h][s][dh]; z=1: K -> same; z=2: V -> [b][h][dh][s]
__global__ __launch_bounds__(256) void proj128_kernel(
    const float* __restrict__ q, const float* __restrict__ k,
    const float* __restrict__ v, const unsigned short* __restrict__ Wb,
    unsigned short* __restrict__ Qb, unsigned short* __restrict__ Kb,
    unsigned short* __restrict__ Vt) {
  __shared__ unsigned short sA[128 * 72];   // padded (ds_write staging)
  __shared__ unsigned short sB[128 * 64];   // unpadded (global_load_lds)

  const int z = blockIdx.z;
  const float* A = (z == 0) ? q : (z == 1) ? k : v;
  const unsigned short* W = Wb + (size_t)z * DD * DD;
  unsigned short* Out = (z == 0) ? Qb : (z == 1) ? Kb : Vt;
  const int layout = (z == 2) ? 1 : 0;

  const int t = threadIdx.x;
  const int lane = t & 63, wave = t >> 6;
  const int quad = lane >> 4, l15 = lane & 15;
  const int wr = wave >> 1, wc = wave & 1;
  const int mBase = blockIdx.x * 128, nBase = blockIdx.y * 128;
  const int arow = t >> 1, ahalf = t & 1;  // A staging: 2 threads/row, 32 floats each

  f32x4 acc[4][4] = {};

  for (int k0 = 0; k0 < DD; k0 += 64) {
    // --- stage B via async global->LDS (4 issues x 4KB) ---
    #pragma unroll
    for (int i = 0; i < 4; ++i) {
      const int brow = i * 32 + wave * 8 + (lane >> 3);
      const unsigned short* g = W + (size_t)(nBase + brow) * DD + k0 + (lane & 7) * 8;
      gload_lds16(g, &sB[(i * 32 + wave * 8) * 64]);
    }
    // --- stage A: fp32 load + convert + ds_write ---
    {
      const float* asrc = A + (size_t)(mBase + arow) * DD + k0 + ahalf * 32;
      #pragma unroll
      for (int j = 0; j < 4; ++j) {
        uint2 lo = pack4(*reinterpret_cast<const float4*>(asrc + j * 8));
        uint2 hi = pack4(*reinterpret_cast<const float4*>(asrc + j * 8 + 4));
        uint4 u; u.x = lo.x; u.y = lo.y; u.z = hi.x; u.w = hi.y;
        *reinterpret_cast<uint4*>(&sA[arow * 72 + ahalf * 32 + j * 8]) = u;
      }
    }
    __syncthreads();

    #pragma unroll
    for (int kk = 0; kk < 2; ++kk) {
      bf16x8 af[4], bfr[4];
      #pragma unroll
      for (int i = 0; i < 4; ++i)
        af[i] = ldsFrag(sA, (wr * 64 + i * 16 + l15) * 72 + kk * 32 + quad * 8);
      #pragma unroll
      for (int j = 0; j < 4; ++j)
        bfr[j] = ldsFrag(sB, (wc * 64 + j * 16 + l15) * 64 + kk * 32 + quad * 8);
      #pragma unroll
      for (int i = 0; i < 4; ++i)
        #pragma unroll
        for (int j = 0; j < 4; ++j)
          acc[i][j] = MFMA16(af[i], bfr[j], acc[i][j]);
    }
    __syncthreads();
  }

  // Epilogue: scatter bf16 to head layout
  #pragma unroll
  for (int i = 0; i < 4; ++i) {
    #pragma unroll
    for (int j = 0; j < 4; ++j) {
      #pragma unroll
      for (int r = 0; r < 4; ++r) {
        int m = mBase + wr * 64 + i * 16 + quad * 4 + r;
        int n = nBase + wc * 64 + j * 16 + l15;
        int b = m >> 11, s = m & (SS - 1);
        int h = n >> 6, dh = n & (DHH - 1);
        size_t off;
        if (layout == 0)
          off = ((size_t)(b * HH + h) * SS + s) * DHH + dh;
        else
          off = ((size_t)(b * HH + h) * DHH + dh) * SS + s;
        Out[off] = f2bf(acc[i][j][r]);
      }
    }
  }
}

// ---------------- folded flash attention ----------------
// Block i handles q-tiles {i, 31-i} -> exactly 33 K-tile iterations per block.
__global__ __launch_bounds__(256) void attn_kernel(
    const unsigned short* __restrict__ Qb, const unsigned short* __restrict__ Kb,
    const unsigned short* __restrict__ Vt, const int* __restrict__ mask,
    unsigned short* __restrict__ Ob) {
  __shared__ unsigned short sQ[64 * 72];
  __shared__ unsigned short sK[64 * 72];
  __shared__ unsigned short sV[64 * 72];
  __shared__ unsigned short sP[64 * 72];
  __shared__ float sPad[64];

  const int t = threadIdx.x;
  const int lane = t & 63, wave = t >> 6;
  const int quad = lane >> 4, l15 = lane & 15;
  const int h = blockIdx.y, b = blockIdx.z;
  const size_t headOff = (size_t)(b * HH + h) * SS * DHH;
  const unsigned short* Qh = Qb + headOff;  // [S][64]
  const unsigned short* Kh = Kb + headOff;  // [S][64]
  const unsigned short* Vh = Vt + headOff;  // [64][S]
  const int row = t >> 2, cg = t & 3;

  #pragma unroll
  for (int phase = 0; phase < 2; ++phase) {
    const int qt = (phase == 0) ? (int)blockIdx.x : (int)(31 - blockIdx.x);
    const int qb = qt * 64;

    // Stage Q tile for this phase
    {
      const uint4* src = reinterpret_cast<const uint4*>(Qh + (size_t)(qb + row) * DHH + cg * 16);
      *reinterpret_cast<uint4*>(&sQ[row * 72 + cg * 16]) = src[0];
      *reinterpret_cast<uint4*>(&sQ[row * 72 + cg * 16 + 8]) = src[1];
    }
    __syncthreads();

    bf16x8 aq[2];
    #pragma unroll
    for (int kk = 0; kk < 2; ++kk)
      aq[kk] = ldsFrag(sQ, (wave * 16 + l15) * 72 + kk * 32 + quad * 8);

    float m_r[4], l_r[4];
    f32x4 oacc[4] = {};
    #pragma unroll
    for (int r = 0; r < 4; ++r) { m_r[r] = -1e30f; l_r[r] = 0.0f; }

    for (int kt = 0; kt <= qt; ++kt) {
      // Stage K tile, V^T tile, padding mask
      {
        const uint4* srcK = reinterpret_cast<const uint4*>(Kh + (size_t)(kt * 64 + row) * DHH + cg * 16);
        *reinterpret_cast<uint4*>(&sK[row * 72 + cg * 16]) = srcK[0];
        *reinterpret_cast<uint4*>(&sK[row * 72 + cg * 16 + 8]) = srcK[1];
        const uint4* srcV = reinterpret_cast<const uint4*>(Vh + (size_t)row * SS + kt * 64 + cg * 16);
        *reinterpret_cast<uint4*>(&sV[row * 72 + cg * 16]) = srcV[0];
        *reinterpret_cast<uint4*>(&sV[row * 72 + cg * 16 + 8]) = srcV[1];
        if (t < 64) sPad[t] = (mask[b * SS + kt * 64 + t] == 0) ? NEGV : 0.0f;
      }
      __syncthreads();

      // S = Q K^T for this wave's 16 q-rows x 64 keys
      f32x4 sacc[4] = {};
      #pragma unroll
      for (int kk = 0; kk < 2; ++kk) {
        #pragma unroll
        for (int j = 0; j < 4; ++j) {
          bf16x8 bk = ldsFrag(sK, (j * 16 + l15) * 72 + kk * 32 + quad * 8);
          sacc[j] = MFMA16(aq[kk], bk, sacc[j]);
        }
      }

      const bool diag = (kt == qt);
      float alpha[4];
      #pragma unroll
      for (int r = 0; r < 4; ++r) {
        const int qrow = qb + wave * 16 + quad * 4 + r;
        float rowmax = -1e30f;
        #pragma unroll
        for (int j = 0; j < 4; ++j) {
          const int kcol = kt * 64 + j * 16 + l15;
          float sv = sacc[j][r] * 0.125f + sPad[j * 16 + l15];
          if (diag && kcol > qrow) sv = NEGV;
          sacc[j][r] = sv;
          rowmax = fmaxf(rowmax, sv);
        }
        #pragma unroll
        for (int off = 1; off < 16; off <<= 1)
          rowmax = fmaxf(rowmax, __shfl_xor(rowmax, off));
        const float mnew = fmaxf(m_r[r], rowmax);
        alpha[r] = __expf(m_r[r] - mnew);
        m_r[r] = mnew;
        float rs = 0.0f;
        #pragma unroll
        for (int j = 0; j < 4; ++j) {
          float p = __expf(sacc[j][r] - mnew);
          rs += p;
          sP[(wave * 16 + quad * 4 + r) * 72 + j * 16 + l15] = f2bf(p);
        }
        #pragma unroll
        for (int off = 1; off < 16; off <<= 1)
          rs += __shfl_xor(rs, off);
        l_r[r] = l_r[r] * alpha[r] + rs;
      }

      // Rescale O accumulator
      #pragma unroll
      for (int jn = 0; jn < 4; ++jn)
        #pragma unroll
        for (int r = 0; r < 4; ++r)
          oacc[jn][r] *= alpha[r];

      // O += P V  (P from per-wave LDS region, V^T gives B^T form)
      #pragma unroll
      for (int kk = 0; kk < 2; ++kk) {
        bf16x8 ap = ldsFrag(sP, (wave * 16 + l15) * 72 + kk * 32 + quad * 8);
        #pragma unroll
        for (int jn = 0; jn < 4; ++jn) {
          bf16x8 bv = ldsFrag(sV, (jn * 16 + l15) * 72 + kk * 32 + quad * 8);
          oacc[jn] = MFMA16(ap, bv, oacc[jn]);
        }
      }
      __syncthreads();
    }

    // Normalize and store O as bf16 [B][S][D] (merged heads)
    #pragma unroll
    for (int r = 0; r < 4; ++r) {
      const float inv = 1.0f / l_r[r];
      const int qrow = qb + wave * 16 + quad * 4 + r;
      #pragma unroll
      for (int jn = 0; jn < 4; ++jn) {
        const int col = h * DHH + jn * 16 + l15;
        Ob[(size_t)(b * SS + qrow) * DD + col] = f2bf(oacc[jn][r] * inv);
      }
    }
  }
}

// ---------------- output projection ----------------
// out = O(bf16, MxK) * Wo(bf16, NxK)^T, fp32 output. Both operands via global_load_lds.
__global__ __launch_bounds__(256) void outproj_kernel(
    const unsigned short* __restrict__ Ag, const unsigned short* __restrict__ Wb,
    float* __restrict__ Out) {
  __shared__ unsigned short sA[128 * 64];   // unpadded
  __shared__ unsigned short sB[128 * 64];   // unpadded

  const unsigned short* W = Wb + (size_t)3 * DD * DD;  // Wo
  const int t = threadIdx.x;
  const int lane = t & 63, wave = t >> 6;
  const int quad = lane >> 4, l15 = lane & 15;
  const int wr = wave >> 1, wc = wave & 1;
  const int mBase = blockIdx.x * 128, nBase = blockIdx.y * 128;

  f32x4 acc[4][4] = {};

  for (int k0 = 0; k0 < DD; k0 += 64) {
    #pragma unroll
    for (int i = 0; i < 4; ++i) {
      const int r8 = i * 32 + wave * 8 + (lane >> 3);
      const int kc = (lane & 7) * 8;
      gload_lds16(Ag + (size_t)(mBase + r8) * DD + k0 + kc, &sA[(i * 32 + wave * 8) * 64]);
      gload_lds16(W + (size_t)(nBase + r8) * DD + k0 + kc, &sB[(i * 32 + wave * 8) * 64]);
    }
    __syncthreads();

    #pragma unroll
    for (int kk = 0; kk < 2; ++kk) {
      bf16x8 af[4], bfr[4];
      #pragma unroll
      for (int i = 0; i < 4; ++i)
        af[i] = ldsFrag(sA, (wr * 64 + i * 16 + l15) * 64 + kk * 32 + quad * 8);
      #pragma unroll
      for (int j = 0; j < 4; ++j)
        bfr[j] = ldsFrag(sB, (wc * 64 + j * 16 + l15) * 64 + kk * 32 + quad * 8);
      #pragma unroll
      for (int i = 0; i < 4; ++i)
        #pragma unroll
        for (int j = 0; j < 4; ++j)
          acc[i][j] = MFMA16(af[i], bfr[j], acc[i][j]);
    }
    __syncthreads();
  }

  #pragma unroll
  for (int i = 0; i < 4; ++i) {
    #pragma unroll
    for (int j = 0; j < 4; ++j) {
      #pragma unroll
      for (int r = 0; r < 4; ++r) {
        int m = mBase + wr * 64 + i * 16 + quad * 4 + r;
        int n = nBase + wc * 64 + j * 16 + l15;
        Out[(size_t)m * DD + n] = acc[i][j][r];
      }
    }
  }
}

extern "C" void kernel_launch(void* const* d_in, const int* in_sizes, int n_in,
                              void* d_out, int out_size, void* d_ws, size_t ws_size,
                              hipStream_t stream) {
  (void)in_sizes; (void)n_in; (void)out_size; (void)ws_size;
  const float* q  = (const float*)d_in[0];
  const float* k  = (const float*)d_in[1];
  const float* v  = (const float*)d_in[2];
  const int* mask = (const int*)d_in[3];
  const float* Wq = (const float*)d_in[4];
  const float* Wk = (const float*)d_in[5];
  const float* Wv = (const float*)d_in[6];
  const float* Wo = (const float*)d_in[7];
  float* out = (float*)d_out;

  const size_t headElems = (size_t)BB * HH * SS * DHH;  // 4M elements
  unsigned short* Qb = (unsigned short*)d_ws;
  unsigned short* Kb = Qb + headElems;
  unsigned short* Vt = Kb + headElems;
  unsigned short* Ob = Vt + headElems;
  unsigned short* Wb = Ob + headElems;   // 4 x DD*DD bf16 (8 MB)

  // 1. convert weights fp32 -> bf16
  convert_kernel<<<dim3(DD * DD / 1024, 4), 256, 0, stream>>>(Wq, Wk, Wv, Wo, Wb);

  // 2. Q/K/V projections (fused launch, z = which)
  proj128_kernel<<<dim3(BB * SS / 128, DD / 128, 3), 256, 0, stream>>>(
      q, k, v, Wb, Qb, Kb, Vt);

  // 3. folded flash attention
  attn_kernel<<<dim3(SS / 128, HH, BB), 256, 0, stream>>>(Qb, Kb, Vt, mask, Ob);

  // 4. output projection
  outproj_kernel<<<dim3(BB * SS / 128, DD / 128), 256, 0, stream>>>(Ob, Wb, out);
}

// Round 3
// 285.004 us; speedup vs baseline: 1.2104x; 1.0469x over previous
//
#include <hip/hip_runtime.h>
#include <stdint.h>

// Problem constants
#define BB 2
#define SS 2048
#define DD 1024
#define HH 16
#define DHH 64
#define NEGV -1.0e9f

typedef __bf16 bf16_t;
typedef bf16_t bf16x8 __attribute__((ext_vector_type(8)));
typedef float f32x4 __attribute__((ext_vector_type(4)));

union FragU { uint4 u; bf16x8 b; };

__device__ __forceinline__ unsigned short f2bf(float f) {
  union { float f; unsigned int u; } x; x.f = f;
  unsigned int u = x.u;
  return (unsigned short)((u + 0x7FFFu + ((u >> 16) & 1u)) >> 16);  // RNE
}

__device__ __forceinline__ uint2 pack4(float4 v) {
  uint2 r;
  r.x = (unsigned)f2bf(v.x) | ((unsigned)f2bf(v.y) << 16);
  r.y = (unsigned)f2bf(v.z) | ((unsigned)f2bf(v.w) << 16);
  return r;
}

__device__ __forceinline__ bf16x8 ldsFrag(const unsigned short* s, int idx) {
  FragU f;
  f.u = *reinterpret_cast<const uint4*>(s + idx);
  return f.b;
}

// async global -> LDS, 16 bytes per lane. LDS dest = wave-uniform base + lane*16.
__device__ __forceinline__ void gload_lds16(const unsigned short* g, unsigned short* s) {
  __builtin_amdgcn_global_load_lds(
      (const __attribute__((address_space(1))) unsigned int*)g,
      (__attribute__((address_space(3))) unsigned int*)s, 16, 0, 0);
}

#define MFMA16(a, b, c) __builtin_amdgcn_mfma_f32_16x16x32_bf16((a), (b), (c), 0, 0, 0)

// ---------------- fp32 -> bf16 convert: activations (z=0..2) + weights (z=3..6) ----------------
__global__ __launch_bounds__(256) void convert_kernel(
    const float* __restrict__ q, const float* __restrict__ k, const float* __restrict__ v,
    const float* __restrict__ Wq, const float* __restrict__ Wk,
    const float* __restrict__ Wv, const float* __restrict__ Wo,
    unsigned short* __restrict__ Ab, unsigned short* __restrict__ Wb) {
  const int z = blockIdx.y;
  const float* src;
  unsigned short* dst;
  if (z < 3) {
    src = (z == 0) ? q : (z == 1) ? k : v;
    dst = Ab + (size_t)z * BB * SS * DD;
  } else {
    if (blockIdx.x >= (DD * DD / 1024)) return;
    src = (z == 3) ? Wq : (z == 4) ? Wk : (z == 5) ? Wv : Wo;
    dst = Wb + (size_t)(z - 3) * DD * DD;
  }
  const size_t base = (size_t)blockIdx.x * 1024 + (size_t)threadIdx.x * 4;
  float4 val = *reinterpret_cast<const float4*>(src + base);
  uint2 p = pack4(val);
  *reinterpret_cast<uint2*>(dst + base) = p;
}

// ---------------- Q/K/V projections (pure bf16, m97 structure) ----------------
// C = A(bf16, MxK) * W(bf16, NxK)^T ; 128x128 tile, BK=64, both operands async-staged.
// z=0: Q -> [b][h][s][dh]; z=1: K -> same; z=2: V -> [b][h][dh][s]
__global__ __launch_bounds__(256) void proj128_kernel(
    const unsigned short* __restrict__ Ab, const unsigned short* __restrict__ Wb,
    unsigned short* __restrict__ Qb, unsigned short* __restrict__ Kb,
    unsigned short* __restrict__ Vt) {
  __shared__ unsigned short sA[128 * 64];
  __shared__ unsigned short sB[128 * 64];

  const int z = blockIdx.z;
  const unsigned short* A = Ab + (size_t)z * BB * SS * DD;
  const unsigned short* W = Wb + (size_t)z * DD * DD;
  unsigned short* Out = (z == 0) ? Qb : (z == 1) ? Kb : Vt;
  const int layout = (z == 2) ? 1 : 0;

  const int t = threadIdx.x;
  const int lane = t & 63, wave = t >> 6;
  const int quad = lane >> 4, l15 = lane & 15;
  const int wr = wave >> 1, wc = wave & 1;
  const int mBase = blockIdx.x * 128, nBase = blockIdx.y * 128;

  f32x4 acc[4][4] = {};

  for (int k0 = 0; k0 < DD; k0 += 64) {
    #pragma unroll
    for (int i = 0; i < 4; ++i) {
      const int r8 = i * 32 + wave * 8 + (lane >> 3);
      const int kc = (lane & 7) * 8;
      gload_lds16(A + (size_t)(mBase + r8) * DD + k0 + kc, &sA[(i * 32 + wave * 8) * 64]);
      gload_lds16(W + (size_t)(nBase + r8) * DD + k0 + kc, &sB[(i * 32 + wave * 8) * 64]);
    }
    __syncthreads();

    #pragma unroll
    for (int kk = 0; kk < 2; ++kk) {
      bf16x8 af[4], bfr[4];
      #pragma unroll
      for (int i = 0; i < 4; ++i)
        af[i] = ldsFrag(sA, (wr * 64 + i * 16 + l15) * 64 + kk * 32 + quad * 8);
      #pragma unroll
      for (int j = 0; j < 4; ++j)
        bfr[j] = ldsFrag(sB, (wc * 64 + j * 16 + l15) * 64 + kk * 32 + quad * 8);
      #pragma unroll
      for (int i = 0; i < 4; ++i)
        #pragma unroll
        for (int j = 0; j < 4; ++j)
          acc[i][j] = MFMA16(af[i], bfr[j], acc[i][j]);
    }
    __syncthreads();
  }

  // Epilogue: scatter bf16 to head layout
  #pragma unroll
  for (int i = 0; i < 4; ++i) {
    #pragma unroll
    for (int j = 0; j < 4; ++j) {
      #pragma unroll
      for (int r = 0; r < 4; ++r) {
        int m = mBase + wr * 64 + i * 16 + quad * 4 + r;
        int n = nBase + wc * 64 + j * 16 + l15;
        int b = m >> 11, s = m & (SS - 1);
        int h = n >> 6, dh = n & (DHH - 1);
        size_t off;
        if (layout == 0)
          off = ((size_t)(b * HH + h) * SS + s) * DHH + dh;
        else
          off = ((size_t)(b * HH + h) * DHH + dh) * SS + s;
        Out[off] = f2bf(acc[i][j][r]);
      }
    }
  }
}

// ---------------- folded flash attention, 128-key chunks, async staging ----------------
// Block i handles q-tiles {i, 31-i} -> exactly 17 chunk-iterations per block.
__global__ __launch_bounds__(256) void attn_kernel(
    const unsigned short* __restrict__ Qb, const unsigned short* __restrict__ Kb,
    const unsigned short* __restrict__ Vt, const int* __restrict__ mask,
    unsigned short* __restrict__ Ob) {
  __shared__ unsigned short sQ[64 * 64];     // [qrow][dh]     async-staged
  __shared__ unsigned short sK[128 * 64];    // [key][dh]      async-staged
  __shared__ unsigned short sV[64 * 128];    // [dh][key]      async-staged
  __shared__ unsigned short sP[64 * 136];    // [qrow][key]    ds_write, padded stride
  __shared__ float sPad[128];

  const int t = threadIdx.x;
  const int lane = t & 63, wave = t >> 6;
  const int quad = lane >> 4, l15 = lane & 15;
  const int h = blockIdx.y, b = blockIdx.z;
  const size_t headOff = (size_t)(b * HH + h) * SS * DHH;
  const unsigned short* Qh = Qb + headOff;  // [S][64]
  const unsigned short* Kh = Kb + headOff;  // [S][64]
  const unsigned short* Vh = Vt + headOff;  // [64][S]

  #pragma unroll
  for (int phase = 0; phase < 2; ++phase) {
    const int qt = (phase == 0) ? (int)blockIdx.x : (int)(31 - blockIdx.x);
    const int qb = qt * 64;

    // Stage Q tile async (64 rows x 128B; 2 calls/wave)
    #pragma unroll
    for (int i = 0; i < 2; ++i) {
      const int row0 = i * 32 + wave * 8;
      gload_lds16(Qh + (size_t)(qb + row0 + (lane >> 3)) * DHH + (lane & 7) * 8,
                  &sQ[row0 * 64]);
    }
    __syncthreads();

    bf16x8 aq[2];
    #pragma unroll
    for (int kk = 0; kk < 2; ++kk)
      aq[kk] = ldsFrag(sQ, (wave * 16 + l15) * 64 + kk * 32 + quad * 8);

    float m_r[4], l_r[4];
    f32x4 oacc[4] = {};
    #pragma unroll
    for (int r = 0; r < 4; ++r) { m_r[r] = -1e30f; l_r[r] = 0.0f; }

    const int nc = (qt + 2) >> 1;  // ceil((qt+1)/2) 128-key chunks
    for (int c = 0; c < nc; ++c) {
      const int c0 = c * 128;
      // stage K chunk (128 rows x 128B; 4 calls/wave)
      #pragma unroll
      for (int i = 0; i < 4; ++i) {
        const int row0 = i * 32 + wave * 8;
        gload_lds16(Kh + (size_t)(c0 + row0 + (lane >> 3)) * DHH + (lane & 7) * 8,
                    &sK[row0 * 64]);
      }
      // stage V^T chunk (64 dh-rows x 256B; 4 calls/wave)
      #pragma unroll
      for (int i = 0; i < 4; ++i) {
        const int r0 = i * 16 + wave * 4;
        gload_lds16(Vh + (size_t)(r0 + (lane >> 4)) * SS + c0 + (lane & 15) * 8,
                    &sV[r0 * 128]);
      }
      if (t < 128) sPad[t] = (mask[b * SS + c0 + t] == 0) ? NEGV : 0.0f;
      __syncthreads();

      // S = Q K^T : 16 q-rows x 128 keys per wave
      f32x4 sacc[8] = {};
      #pragma unroll
      for (int kk = 0; kk < 2; ++kk) {
        #pragma unroll
        for (int j = 0; j < 8; ++j) {
          bf16x8 bk = ldsFrag(sK, (j * 16 + l15) * 64 + kk * 32 + quad * 8);
          sacc[j] = MFMA16(aq[kk], bk, sacc[j]);
        }
      }

      float alpha[4];
      #pragma unroll
      for (int r = 0; r < 4; ++r) {
        const int qrow = qb + wave * 16 + quad * 4 + r;
        float rowmax = -1e30f;
        #pragma unroll
        for (int j = 0; j < 8; ++j) {
          const int kcol = c0 + j * 16 + l15;
          float sv = sacc[j][r] * 0.125f + sPad[j * 16 + l15];
          if (kcol > qrow) sv = NEGV;
          sacc[j][r] = sv;
          rowmax = fmaxf(rowmax, sv);
        }
        #pragma unroll
        for (int off = 1; off < 16; off <<= 1)
          rowmax = fmaxf(rowmax, __shfl_xor(rowmax, off));
        const float mnew = fmaxf(m_r[r], rowmax);
        alpha[r] = __expf(m_r[r] - mnew);
        m_r[r] = mnew;
        float rs = 0.0f;
        #pragma unroll
        for (int j = 0; j < 8; ++j) {
          float p = __expf(sacc[j][r] - mnew);
          rs += p;
          sP[(wave * 16 + quad * 4 + r) * 136 + j * 16 + l15] = f2bf(p);
        }
        #pragma unroll
        for (int off = 1; off < 16; off <<= 1)
          rs += __shfl_xor(rs, off);
        l_r[r] = l_r[r] * alpha[r] + rs;
      }

      // Rescale O accumulator
      #pragma unroll
      for (int jn = 0; jn < 4; ++jn)
        #pragma unroll
        for (int r = 0; r < 4; ++r)
          oacc[jn][r] *= alpha[r];

      // O += P V (sP per-wave region; sV shared, staged above)
      #pragma unroll
      for (int kk = 0; kk < 4; ++kk) {
        bf16x8 ap = ldsFrag(sP, (wave * 16 + l15) * 136 + kk * 32 + quad * 8);
        #pragma unroll
        for (int jn = 0; jn < 4; ++jn) {
          bf16x8 bv = ldsFrag(sV, (jn * 16 + l15) * 128 + kk * 32 + quad * 8);
          oacc[jn] = MFMA16(ap, bv, oacc[jn]);
        }
      }
      __syncthreads();
    }

    // Normalize and store O as bf16 [B][S][D] (merged heads)
    #pragma unroll
    for (int r = 0; r < 4; ++r) {
      const float inv = 1.0f / l_r[r];
      const int qrow = qb + wave * 16 + quad * 4 + r;
      #pragma unroll
      for (int jn = 0; jn < 4; ++jn) {
        const int col = h * DHH + jn * 16 + l15;
        Ob[(size_t)(b * SS + qrow) * DD + col] = f2bf(oacc[jn][r] * inv);
      }
    }
  }
}

// ---------------- output projection ----------------
// out = O(bf16, MxK) * Wo(bf16, NxK)^T, fp32 output. Both operands via global_load_lds.
__global__ __launch_bounds__(256) void outproj_kernel(
    const unsigned short* __restrict__ Ag, const unsigned short* __restrict__ Wb,
    float* __restrict__ Out) {
  __shared__ unsigned short sA[128 * 64];
  __shared__ unsigned short sB[128 * 64];

  const unsigned short* W = Wb + (size_t)3 * DD * DD;  // Wo
  const int t = threadIdx.x;
  const int lane = t & 63, wave = t >> 6;
  const int quad = lane >> 4, l15 = lane & 15;
  const int wr = wave >> 1, wc = wave & 1;
  const int mBase = blockIdx.x * 128, nBase = blockIdx.y * 128;

  f32x4 acc[4][4] = {};

  for (int k0 = 0; k0 < DD; k0 += 64) {
    #pragma unroll
    for (int i = 0; i < 4; ++i) {
      const int r8 = i * 32 + wave * 8 + (lane >> 3);
      const int kc = (lane & 7) * 8;
      gload_lds16(Ag + (size_t)(mBase + r8) * DD + k0 + kc, &sA[(i * 32 + wave * 8) * 64]);
      gload_lds16(W + (size_t)(nBase + r8) * DD + k0 + kc, &sB[(i * 32 + wave * 8) * 64]);
    }
    __syncthreads();

    #pragma unroll
    for (int kk = 0; kk < 2; ++kk) {
      bf16x8 af[4], bfr[4];
      #pragma unroll
      for (int i = 0; i < 4; ++i)
        af[i] = ldsFrag(sA, (wr * 64 + i * 16 + l15) * 64 + kk * 32 + quad * 8);
      #pragma unroll
      for (int j = 0; j < 4; ++j)
        bfr[j] = ldsFrag(sB, (wc * 64 + j * 16 + l15) * 64 + kk * 32 + quad * 8);
      #pragma unroll
      for (int i = 0; i < 4; ++i)
        #pragma unroll
        for (int j = 0; j < 4; ++j)
          acc[i][j] = MFMA16(af[i], bfr[j], acc[i][j]);
    }
    __syncthreads();
  }

  #pragma unroll
  for (int i = 0; i < 4; ++i) {
    #pragma unroll
    for (int j = 0; j < 4; ++j) {
      #pragma unroll
      for (int r = 0; r < 4; ++r) {
        int m = mBase + wr * 64 + i * 16 + quad * 4 + r;
        int n = nBase + wc * 64 + j * 16 + l15;
        Out[(size_t)m * DD + n] = acc[i][j][r];
      }
    }
  }
}

extern "C" void kernel_launch(void* const* d_in, const int* in_sizes, int n_in,
                              void* d_out, int out_size, void* d_ws, size_t ws_size,
                              hipStream_t stream) {
  (void)in_sizes; (void)n_in; (void)out_size; (void)ws_size;
  const float* q  = (const float*)d_in[0];
  const float* k  = (const float*)d_in[1];
  const float* v  = (const float*)d_in[2];
  const int* mask = (const int*)d_in[3];
  const float* Wq = (const float*)d_in[4];
  const float* Wk = (const float*)d_in[5];
  const float* Wv = (const float*)d_in[6];
  const float* Wo = (const float*)d_in[7];
  float* out = (float*)d_out;

  const size_t AE = (size_t)BB * SS * DD;  // 4M elements per activation
  unsigned short* Ab = (unsigned short*)d_ws;       // 3 x AE bf16 (24 MB)
  unsigned short* Ob = Ab;                          // aliases Ab (dead after proj)
  unsigned short* Wb = Ab + 3 * AE;                 // 4 x DD*DD bf16 (8 MB)
  unsigned short* Qb = Wb + (size_t)4 * DD * DD;    // 8 MB each
  unsigned short* Kb = Qb + AE;
  unsigned short* Vt = Kb + AE;

  // 1. convert activations + weights fp32 -> bf16
  convert_kernel<<<dim3(AE / 1024, 7), 256, 0, stream>>>(q, k, v, Wq, Wk, Wv, Wo, Ab, Wb);

  // 2. Q/K/V projections (fused launch, z = which)
  proj128_kernel<<<dim3(BB * SS / 128, DD / 128, 3), 256, 0, stream>>>(
      Ab, Wb, Qb, Kb, Vt);

  // 3. folded flash attention (128-key chunks)
  attn_kernel<<<dim3(SS / 128, HH, BB), 256, 0, stream>>>(Qb, Kb, Vt, mask, Ob);

  // 4. output projection
  outproj_kernel<<<dim3(BB * SS / 128, DD / 128), 256, 0, stream>>>(Ob, Wb, out);
}

// Round 4
// 237.600 us; speedup vs baseline: 1.4519x; 1.1995x over previous
//
#include <hip/hip_runtime.h>
#include <stdint.h>

// Problem constants
#define BB 2
#define SS 2048
#define DD 1024
#define HH 16
#define DHH 64

typedef __bf16 bf16_t;
typedef bf16_t bf16x8 __attribute__((ext_vector_type(8)));
typedef float f32x4 __attribute__((ext_vector_type(4)));

union FragU { uint4 u; bf16x8 b; };

__device__ __forceinline__ unsigned short f2bf(float f) {
  union { float f; unsigned int u; } x; x.f = f;
  unsigned int u = x.u;
  return (unsigned short)((u + 0x7FFFu + ((u >> 16) & 1u)) >> 16);  // RNE
}

__device__ __forceinline__ uint2 pack4(float4 v) {
  uint2 r;
  r.x = (unsigned)f2bf(v.x) | ((unsigned)f2bf(v.y) << 16);
  r.y = (unsigned)f2bf(v.z) | ((unsigned)f2bf(v.w) << 16);
  return r;
}

__device__ __forceinline__ bf16x8 ldsFrag(const unsigned short* s, int idx) {
  FragU f;
  f.u = *reinterpret_cast<const uint4*>(s + idx);
  return f.b;
}

// async global -> LDS, 16 bytes per lane. LDS dest = wave-uniform base + lane*16.
__device__ __forceinline__ void gload_lds16(const unsigned short* g, unsigned short* s) {
  __builtin_amdgcn_global_load_lds(
      (const __attribute__((address_space(1))) unsigned int*)g,
      (__attribute__((address_space(3))) unsigned int*)s, 16, 0, 0);
}

#define MFMA16(a, b, c) __builtin_amdgcn_mfma_f32_16x16x32_bf16((a), (b), (c), 0, 0, 0)

// ---------------- fp32 -> bf16 convert: activations (z=0..2) + weights (z=3..6) ----------------
// Wq (z==3) is pre-scaled by 1/8 (attention score scale folded in).
__global__ __launch_bounds__(256) void convert_kernel(
    const float* __restrict__ q, const float* __restrict__ k, const float* __restrict__ v,
    const float* __restrict__ Wq, const float* __restrict__ Wk,
    const float* __restrict__ Wv, const float* __restrict__ Wo,
    unsigned short* __restrict__ Ab, unsigned short* __restrict__ Wb) {
  const int z = blockIdx.y;
  const float* src;
  unsigned short* dst;
  float scale = 1.0f;
  if (z < 3) {
    src = (z == 0) ? q : (z == 1) ? k : v;
    dst = Ab + (size_t)z * BB * SS * DD;
  } else {
    if (blockIdx.x >= (DD * DD / 1024)) return;
    src = (z == 3) ? Wq : (z == 4) ? Wk : (z == 5) ? Wv : Wo;
    dst = Wb + (size_t)(z - 3) * DD * DD;
    if (z == 3) scale = 0.125f;
  }
  const size_t base = (size_t)blockIdx.x * 1024 + (size_t)threadIdx.x * 4;
  float4 val = *reinterpret_cast<const float4*>(src + base);
  val.x *= scale; val.y *= scale; val.z *= scale; val.w *= scale;
  uint2 p = pack4(val);
  *reinterpret_cast<uint2*>(dst + base) = p;
}

// ---------------- Q/K/V projections (pure bf16, xor-swizzled LDS) ----------------
// C = A(bf16, MxK) * W(bf16, NxK)^T ; 128x128 tile, BK=64, both operands async-staged.
// LDS layout: unit(16B) = row*8 + (koct ^ (row&7))  -> conflict-free frag reads.
// z=0: Q -> [b][h][s][dh]; z=1: K -> same; z=2: V -> [b][h][dh][s]
__global__ __launch_bounds__(256) void proj128_kernel(
    const unsigned short* __restrict__ Ab, const unsigned short* __restrict__ Wb,
    unsigned short* __restrict__ Qb, unsigned short* __restrict__ Kb,
    unsigned short* __restrict__ Vt) {
  __shared__ unsigned short sA[128 * 64];
  __shared__ unsigned short sB[128 * 64];

  const int z = blockIdx.z;
  const unsigned short* A = Ab + (size_t)z * BB * SS * DD;
  const unsigned short* W = Wb + (size_t)z * DD * DD;
  unsigned short* Out = (z == 0) ? Qb : (z == 1) ? Kb : Vt;
  const int layout = (z == 2) ? 1 : 0;

  const int t = threadIdx.x;
  const int lane = t & 63, wave = t >> 6;
  const int quad = lane >> 4, l15 = lane & 15;
  const int wr = wave >> 1, wc = wave & 1;
  const int mBase = blockIdx.x * 128, nBase = blockIdx.y * 128;

  f32x4 acc[4][4] = {};

  for (int k0 = 0; k0 < DD; k0 += 64) {
    #pragma unroll
    for (int i = 0; i < 4; ++i) {
      const int g = wave * 4 + i;
      const int row = g * 8 + (lane >> 3);
      const int oct = (lane & 7) ^ (row & 7);
      gload_lds16(A + (size_t)(mBase + row) * DD + k0 + oct * 8, &sA[g * 512]);
      gload_lds16(W + (size_t)(nBase + row) * DD + k0 + oct * 8, &sB[g * 512]);
    }
    __syncthreads();

    #pragma unroll
    for (int kk = 0; kk < 2; ++kk) {
      bf16x8 af[4], bfr[4];
      #pragma unroll
      for (int i = 0; i < 4; ++i) {
        const int row = wr * 64 + i * 16 + l15;
        af[i] = ldsFrag(sA, (row * 8 + ((kk * 4 + quad) ^ (l15 & 7))) * 8);
      }
      #pragma unroll
      for (int j = 0; j < 4; ++j) {
        const int row = wc * 64 + j * 16 + l15;
        bfr[j] = ldsFrag(sB, (row * 8 + ((kk * 4 + quad) ^ (l15 & 7))) * 8);
      }
      #pragma unroll
      for (int i = 0; i < 4; ++i)
        #pragma unroll
        for (int j = 0; j < 4; ++j)
          acc[i][j] = MFMA16(af[i], bfr[j], acc[i][j]);
    }
    __syncthreads();
  }

  // Epilogue: scatter bf16 to head layout
  #pragma unroll
  for (int i = 0; i < 4; ++i) {
    #pragma unroll
    for (int j = 0; j < 4; ++j) {
      #pragma unroll
      for (int r = 0; r < 4; ++r) {
        int m = mBase + wr * 64 + i * 16 + quad * 4 + r;
        int n = nBase + wc * 64 + j * 16 + l15;
        int b = m >> 11, s = m & (SS - 1);
        int h = n >> 6, dh = n & (DHH - 1);
        size_t off;
        if (layout == 0)
          off = ((size_t)(b * HH + h) * SS + s) * DHH + dh;
        else
          off = ((size_t)(b * HH + h) * DHH + dh) * SS + s;
        Out[off] = f2bf(acc[i][j][r]);
      }
    }
  }
}

// ---------------- folded flash attention ----------------
// Block i handles q-tiles {i, 31-i}: 17 128-key chunks total. Q pre-scaled by 1/8.
// sK/sV xor-swizzled (conflict-free). P stored column-major bf16 (truncated),
// row-sums via ones-column MFMA accumulator (oacc[4]) -> l needs no shuffles.
__global__ __launch_bounds__(256) void attn_kernel(
    const unsigned short* __restrict__ Qb, const unsigned short* __restrict__ Kb,
    const unsigned short* __restrict__ Vt, const int* __restrict__ mask,
    unsigned short* __restrict__ Ob) {
  // sK 16384B | sV 16384B | sPT 17408B (sQ 8192B overlays sPT)
  __shared__ __align__(16) char smem[16384 + 16384 + 17408];
  unsigned short* sK  = (unsigned short*)smem;
  unsigned short* sV  = (unsigned short*)(smem + 16384);
  unsigned short* sPT = (unsigned short*)(smem + 32768);  // [key 128][row 64] stride 68
  unsigned short* sQ  = sPT;                              // overlay, per-phase

  const int t = threadIdx.x;
  const int lane = t & 63, wave = t >> 6;
  const int quad = lane >> 4, l15 = lane & 15;
  const int h = blockIdx.y, b = blockIdx.z;
  const size_t headOff = (size_t)(b * HH + h) * SS * DHH;
  const unsigned short* Qh = Qb + headOff;  // [S][64]
  const unsigned short* Kh = Kb + headOff;  // [S][64]
  const unsigned short* Vh = Vt + headOff;  // [64][S]
  const int* maskp = mask + b * SS;

  FragU onesU;
  onesU.u.x = 0x3F803F80u; onesU.u.y = 0x3F803F80u;
  onesU.u.z = 0x3F803F80u; onesU.u.w = 0x3F803F80u;
  const bf16x8 ones = onesU.b;

  #pragma unroll
  for (int phase = 0; phase < 2; ++phase) {
    const int qt = (phase == 0) ? (int)blockIdx.x : (int)(31 - blockIdx.x);
    const int qb = qt * 64;

    // Stage Q tile (row-major swizzled, 2 issues/wave)
    #pragma unroll
    for (int i = 0; i < 2; ++i) {
      const int g = wave * 2 + i;
      const int row = g * 8 + (lane >> 3);
      const int oct = (lane & 7) ^ (row & 7);
      gload_lds16(Qh + (size_t)(qb + row) * DHH + oct * 8, &sQ[g * 512]);
    }
    __syncthreads();

    bf16x8 aq[2];
    #pragma unroll
    for (int kk = 0; kk < 2; ++kk) {
      const int row = wave * 16 + l15;
      aq[kk] = ldsFrag(sQ, (row * 8 + ((kk * 4 + quad) ^ (l15 & 7))) * 8);
    }

    float m_r[4];
    f32x4 oacc[5] = {};
    #pragma unroll
    for (int r = 0; r < 4; ++r) m_r[r] = -1e30f;

    const int nc = (qt + 2) >> 1;  // ceil((qt+1)/2) 128-key chunks
    const int qrow0 = qb + wave * 16 + quad * 4;
    for (int c = 0; c < nc; ++c) {
      const int c0 = c * 128;
      // stage K chunk: [key 128][dh 64], swizzled
      #pragma unroll
      for (int i = 0; i < 4; ++i) {
        const int g = wave * 4 + i;
        const int row = g * 8 + (lane >> 3);
        const int oct = (lane & 7) ^ (row & 7);
        gload_lds16(Kh + (size_t)(c0 + row) * DHH + oct * 8, &sK[g * 512]);
      }
      // stage V^T chunk: [dh 64][key 128], 16 octets/row swizzled
      #pragma unroll
      for (int i = 0; i < 4; ++i) {
        const int g = wave * 4 + i;
        const int row = g * 4 + (lane >> 4);
        const int oct = (lane & 15) ^ (row & 15);
        gload_lds16(Vh + (size_t)row * SS + c0 + oct * 8, &sV[g * 512]);
      }
      // padding multiplier (mask is 0/1)
      float padmul[8];
      #pragma unroll
      for (int j = 0; j < 8; ++j)
        padmul[j] = (float)maskp[c0 + j * 16 + l15];
      __syncthreads();

      // S = Q K^T : 16 q-rows x 128 keys per wave (Q pre-scaled)
      f32x4 sacc[8] = {};
      #pragma unroll
      for (int kk = 0; kk < 2; ++kk) {
        #pragma unroll
        for (int j = 0; j < 8; ++j) {
          const int row = j * 16 + l15;
          bf16x8 bk = ldsFrag(sK, (row * 8 + ((kk * 4 + quad) ^ (l15 & 7))) * 8);
          sacc[j] = MFMA16(aq[kk], bk, sacc[j]);
        }
      }

      // pass 1: row max (over raw scores -- overestimate is exact for softmax)
      float mnew[4], alpha[4];
      #pragma unroll
      for (int r = 0; r < 4; ++r) {
        float rm = fmaxf(fmaxf(fmaxf(sacc[0][r], sacc[1][r]), fmaxf(sacc[2][r], sacc[3][r])),
                         fmaxf(fmaxf(sacc[4][r], sacc[5][r]), fmaxf(sacc[6][r], sacc[7][r])));
        #pragma unroll
        for (int off = 1; off < 16; off <<= 1)
          rm = fmaxf(rm, __shfl_xor(rm, off));
        mnew[r] = fmaxf(m_r[r], rm);
        alpha[r] = __expf(m_r[r] - mnew[r]);
        m_r[r] = mnew[r];
      }

      // pass 2: p = exp(s-m)*pad (causal zero on diagonal chunk), pack 4 rows -> b64
      const bool diag = (c == nc - 1);
      #pragma unroll
      for (int j = 0; j < 8; ++j) {
        float p0 = __expf(sacc[j][0] - mnew[0]) * padmul[j];
        float p1 = __expf(sacc[j][1] - mnew[1]) * padmul[j];
        float p2 = __expf(sacc[j][2] - mnew[2]) * padmul[j];
        float p3 = __expf(sacc[j][3] - mnew[3]) * padmul[j];
        if (diag) {
          const int kcol = c0 + j * 16 + l15;
          p0 = (kcol > qrow0 + 0) ? 0.0f : p0;
          p1 = (kcol > qrow0 + 1) ? 0.0f : p1;
          p2 = (kcol > qrow0 + 2) ? 0.0f : p2;
          p3 = (kcol > qrow0 + 3) ? 0.0f : p3;
        }
        uint2 w;
        w.x = __builtin_amdgcn_perm(__float_as_uint(p1), __float_as_uint(p0), 0x07060302u);
        w.y = __builtin_amdgcn_perm(__float_as_uint(p3), __float_as_uint(p2), 0x07060302u);
        *reinterpret_cast<uint2*>(&sPT[(j * 16 + l15) * 68 + wave * 16 + quad * 4]) = w;
      }

      // rescale all 5 accumulators (col 4 = row-sum l)
      #pragma unroll
      for (int jn = 0; jn < 5; ++jn)
        #pragma unroll
        for (int r = 0; r < 4; ++r)
          oacc[jn][r] *= alpha[r];

      // O += P V ; l += P * ones
      #pragma unroll
      for (int kk = 0; kk < 4; ++kk) {
        bf16x8 ap;
        #pragma unroll
        for (int jj = 0; jj < 8; ++jj)
          ap[jj] = *reinterpret_cast<const bf16_t*>(
              &sPT[(kk * 32 + quad * 8 + jj) * 68 + wave * 16 + l15]);
        #pragma unroll
        for (int jn = 0; jn < 4; ++jn) {
          const int row = jn * 16 + l15;
          bf16x8 bv = ldsFrag(sV, (row * 16 + ((kk * 4 + quad) ^ l15)) * 8);
          oacc[jn] = MFMA16(ap, bv, oacc[jn]);
        }
        oacc[4] = MFMA16(ap, ones, oacc[4]);
      }
      __syncthreads();
    }

    // Normalize by l (= oacc[4]) and store O as bf16 [B][S][D] (merged heads)
    #pragma unroll
    for (int r = 0; r < 4; ++r) {
      const float inv = 1.0f / oacc[4][r];
      const int qrow = qrow0 + r;
      #pragma unroll
      for (int jn = 0; jn < 4; ++jn) {
        const int col = h * DHH + jn * 16 + l15;
        Ob[(size_t)(b * SS + qrow) * DD + col] = f2bf(oacc[jn][r] * inv);
      }
    }
  }
}

// ---------------- output projection ----------------
// out = O(bf16, MxK) * Wo(bf16, NxK)^T, fp32 output. Swizzled LDS.
__global__ __launch_bounds__(256) void outproj_kernel(
    const unsigned short* __restrict__ Ag, const unsigned short* __restrict__ Wb,
    float* __restrict__ Out) {
  __shared__ unsigned short sA[128 * 64];
  __shared__ unsigned short sB[128 * 64];

  const unsigned short* W = Wb + (size_t)3 * DD * DD;  // Wo
  const int t = threadIdx.x;
  const int lane = t & 63, wave = t >> 6;
  const int quad = lane >> 4, l15 = lane & 15;
  const int wr = wave >> 1, wc = wave & 1;
  const int mBase = blockIdx.x * 128, nBase = blockIdx.y * 128;

  f32x4 acc[4][4] = {};

  for (int k0 = 0; k0 < DD; k0 += 64) {
    #pragma unroll
    for (int i = 0; i < 4; ++i) {
      const int g = wave * 4 + i;
      const int row = g * 8 + (lane >> 3);
      const int oct = (lane & 7) ^ (row & 7);
      gload_lds16(Ag + (size_t)(mBase + row) * DD + k0 + oct * 8, &sA[g * 512]);
      gload_lds16(W + (size_t)(nBase + row) * DD + k0 + oct * 8, &sB[g * 512]);
    }
    __syncthreads();

    #pragma unroll
    for (int kk = 0; kk < 2; ++kk) {
      bf16x8 af[4], bfr[4];
      #pragma unroll
      for (int i = 0; i < 4; ++i) {
        const int row = wr * 64 + i * 16 + l15;
        af[i] = ldsFrag(sA, (row * 8 + ((kk * 4 + quad) ^ (l15 & 7))) * 8);
      }
      #pragma unroll
      for (int j = 0; j < 4; ++j) {
        const int row = wc * 64 + j * 16 + l15;
        bfr[j] = ldsFrag(sB, (row * 8 + ((kk * 4 + quad) ^ (l15 & 7))) * 8);
      }
      #pragma unroll
      for (int i = 0; i < 4; ++i)
        #pragma unroll
        for (int j = 0; j < 4; ++j)
          acc[i][j] = MFMA16(af[i], bfr[j], acc[i][j]);
    }
    __syncthreads();
  }

  #pragma unroll
  for (int i = 0; i < 4; ++i) {
    #pragma unroll
    for (int j = 0; j < 4; ++j) {
      #pragma unroll
      for (int r = 0; r < 4; ++r) {
        int m = mBase + wr * 64 + i * 16 + quad * 4 + r;
        int n = nBase + wc * 64 + j * 16 + l15;
        Out[(size_t)m * DD + n] = acc[i][j][r];
      }
    }
  }
}

extern "C" void kernel_launch(void* const* d_in, const int* in_sizes, int n_in,
                              void* d_out, int out_size, void* d_ws, size_t ws_size,
                              hipStream_t stream) {
  (void)in_sizes; (void)n_in; (void)out_size; (void)ws_size;
  const float* q  = (const float*)d_in[0];
  const float* k  = (const float*)d_in[1];
  const float* v  = (const float*)d_in[2];
  const int* mask = (const int*)d_in[3];
  const float* Wq = (const float*)d_in[4];
  const float* Wk = (const float*)d_in[5];
  const float* Wv = (const float*)d_in[6];
  const float* Wo = (const float*)d_in[7];
  float* out = (float*)d_out;

  const size_t AE = (size_t)BB * SS * DD;  // 4M elements per activation
  unsigned short* Ab = (unsigned short*)d_ws;       // 3 x AE bf16 (24 MB)
  unsigned short* Ob = Ab;                          // aliases Ab (dead after proj)
  unsigned short* Wb = Ab + 3 * AE;                 // 4 x DD*DD bf16 (8 MB)
  unsigned short* Qb = Wb + (size_t)4 * DD * DD;    // 8 MB each
  unsigned short* Kb = Qb + AE;
  unsigned short* Vt = Kb + AE;

  // 1. convert activations + weights fp32 -> bf16 (Wq pre-scaled by 1/8)
  convert_kernel<<<dim3(AE / 1024, 7), 256, 0, stream>>>(q, k, v, Wq, Wk, Wv, Wo, Ab, Wb);

  // 2. Q/K/V projections (fused launch, z = which)
  proj128_kernel<<<dim3(BB * SS / 128, DD / 128, 3), 256, 0, stream>>>(
      Ab, Wb, Qb, Kb, Vt);

  // 3. folded flash attention (128-key chunks)
  attn_kernel<<<dim3(SS / 128, HH, BB), 256, 0, stream>>>(Qb, Kb, Vt, mask, Ob);

  // 4. output projection
  outproj_kernel<<<dim3(BB * SS / 128, DD / 128), 256, 0, stream>>>(Ob, Wb, out);
}